// Round 11
// baseline (82.560 us; speedup 1.0000x reference)
//
#include <hip/hip_runtime.h>
#include <math.h>

// Chamfer loss, two 16384x3 fp32 clouds.
// R15: R14 falsified block-churn (512 vs 2048 blocks: flat). Remaining model
// that fits all data: per-iter serial chain ~235 cyc (exposed lgkm wait ~120
// because b's are read at iter top and the sched_barrier box blocks hoisting,
// + issues + box + 32 min3) vs 129 cyc matrix work. Fix: single-set lagged
// pipeline -- per iter {prefetch nb -> box -> fold P (issued LAST iter,
// >=100cyc old, safer than R10's proven ~30cyc gap) -> issue new P -> b=nb}.
// ds latency and MFMA latency both leave the chain; no parity/rotation
// (single set P rotates in place; fold-before-reissue makes WAR safe).
// ~184 VGPR, no cap. Predicted: main 22 -> ~9-13us, matrix-pipe-bound.

typedef __attribute__((ext_vector_type(8)))  short bf16x8;   // 8 bf16 = 4 VGPR
typedef __attribute__((ext_vector_type(16))) float f32x16;   // MFMA C/D

#define S_SLICES 4    // outer col slices; each block stages 4 chunks of 1024

// Monotone float->uint map: a<b  <=>  enc(a)<enc(b).
__device__ __forceinline__ unsigned enc_f32(float f) {
    int b = __float_as_int(f);
    return (b >= 0) ? ((unsigned)b | 0x80000000u) : ~(unsigned)b;
}
__device__ __forceinline__ float dec_f32(unsigned k) {
    int b = (k & 0x80000000u) ? (int)(k & 0x7FFFFFFFu) : ~(int)k;
    return __int_as_float(b);
}

// fp32 -> bf16 (RNE), and back.
__device__ __forceinline__ unsigned short f2bf(float v) {
    unsigned u = __float_as_uint(v);
    u += 0x7FFFu + ((u >> 16) & 1u);
    return (unsigned short)(u >> 16);
}
__device__ __forceinline__ float bf2f(unsigned short b) {
    unsigned u = ((unsigned)b) << 16;
    return __uint_as_float(u);
}
__device__ __forceinline__ unsigned pk2(unsigned short lo, unsigned short hi) {
    return (unsigned)lo | ((unsigned)hi << 16);
}

__device__ __forceinline__ f32x16 mfma_v(bf16x8 a, bf16x8 b, f32x16 c) {
    f32x16 d;
    asm("v_mfma_f32_32x32x16_bf16 %0, %1, %2, %3"
        : "=&v"(d) : "v"(a), "v"(b), "v"(c));
    return d;
}

// Build A-role and B-role K=16 fragments for every point of both clouds.
// d = |q|^2 + |p|^2 - 2(qh+ql).(ph+pl), all cross terms in the 16 K slots.
// B-role fragments scattered into LDS-friendly order:
//   pos(col j, half h) = (j>>6)*128 + ((j>>5)&1)*64 + h*32 + (j&31).
__global__ __launch_bounds__(256) void chamfer_prep(
    const float* __restrict__ state_x, const float* __restrict__ target,
    uint4* __restrict__ AfragS, uint4* __restrict__ AfragT,
    uint4* __restrict__ BfragS, uint4* __restrict__ BfragT,
    unsigned* __restrict__ mins_u, float* __restrict__ out, int N)
{
    const int p = blockIdx.x * 256 + threadIdx.x;     // [0, 2N)
    const float* src = (p < N) ? state_x : target;
    const int i = (p < N) ? p : p - N;

    const float x = src[3*i+0], y = src[3*i+1], z = src[3*i+2];
    const float n2 = fmaf(x, x, fmaf(y, y, z * z));

    const unsigned short hx = f2bf(x), hy = f2bf(y), hz = f2bf(z);
    const unsigned short lx = f2bf(x - bf2f(hx));
    const unsigned short ly = f2bf(y - bf2f(hy));
    const unsigned short lz = f2bf(z - bf2f(hz));
    const unsigned short mhx = f2bf(-2.0f*x), mhy = f2bf(-2.0f*y), mhz = f2bf(-2.0f*z);
    const unsigned short mlx = f2bf(-2.0f*x - bf2f(mhx));
    const unsigned short mly = f2bf(-2.0f*y - bf2f(mhy));
    const unsigned short mlz = f2bf(-2.0f*z - bf2f(mhz));
    const unsigned short hn = f2bf(n2);
    const unsigned short ln = f2bf(n2 - bf2f(hn));
    const unsigned short ONE = 0x3F80;

    // A-role: [mh(3), ml(3), mh(3), ml(3), hn, ln, 1, 1]
    uint4 A0 = make_uint4(pk2(mhx,mhy), pk2(mhz,mlx), pk2(mly,mlz), pk2(mhx,mhy));
    uint4 A1 = make_uint4(pk2(mhz,mlx), pk2(mly,mlz), pk2(hn,ln),   pk2(ONE,ONE));
    // B-role: [h(3), h(3), l(3), l(3), 1, 1, hn, ln]
    uint4 B0 = make_uint4(pk2(hx,hy), pk2(hz,hx), pk2(hy,hz), pk2(lx,ly));
    uint4 B1 = make_uint4(pk2(lz,lx), pk2(ly,lz), pk2(ONE,ONE), pk2(hn,ln));

    uint4* Aarr = (p < N) ? AfragS : AfragT;
    uint4* Barr = (p < N) ? BfragS : BfragT;
    Aarr[2*i+0] = A0;  Aarr[2*i+1] = A1;

    const int bbase = (i >> 6) * 128 + ((i >> 5) & 1) * 64 + (i & 31);
    Barr[bbase +  0] = B0;   // half 0
    Barr[bbase + 32] = B1;   // half 1

    mins_u[p] = 0xFFFFFFFFu;
    if (p == 0) *out = 0.0f;
}

#define HAZARD_BOX()  do { __builtin_amdgcn_sched_barrier(0); \
                           asm volatile("s_nop 7");           \
                           __builtin_amdgcn_sched_barrier(0); } while (0)

// Main: block = 4 waves x 64 rows = 256 query rows; 4 staged 1024-col
// chunks. Single-set lagged pipeline: fold P (1 iter old) -> issue new P.
__global__ __launch_bounds__(256) void chamfer_main(
    const bf16x8* __restrict__ AfragS, const bf16x8* __restrict__ AfragT,
    const bf16x8* __restrict__ BfragS, const bf16x8* __restrict__ BfragT,
    unsigned* __restrict__ mins_u, int N, int S)
{
    const int tid  = threadIdx.x;
    const int lane = tid & 63;
    const int l31  = lane & 31;
    const int half = lane >> 5;
    const int w    = tid >> 6;

    const int bs = blockIdx.x / S;            // row-block (256 rows)
    const int s  = blockIdx.x % S;            // outer col slice
    const int qblk = bs * 256;                // [0, 2N), never straddles N

    const bf16x8* afr;
    const bf16x8* bfr;
    if (qblk < N) { afr = AfragT + (size_t)qblk * 2;       bfr = BfragS; }
    else          { afr = AfragS + (size_t)(qblk - N) * 2; bfr = BfragT; }

    const int CS = N / S;                     // cols per outer slice (4096)

    __shared__ uint4 ldsB[2048];
    const bf16x8* lb = (const bf16x8*)ldsB;

    // A fragments for this wave's two 32-row tiles (rows w*64 .. w*64+63).
    const int r0 = w * 64;
    const bf16x8 av0 = afr[(r0 +      l31) * 2 + half];
    const bf16x8 av1 = afr[(r0 + 32 + l31) * 2 + half];

    const int boff = half * 32 + l31;

    f32x16 racc0, racc1, zc;
    #pragma unroll
    for (int i = 0; i < 16; ++i) { racc0[i] = 3.0e38f; racc1[i] = 3.0e38f; zc[i] = 0.0f; }

    f32x16 p0, p1, p2, p3;                    // the single pending MFMA set
    bf16x8 b0, b1, nb0, nb1;

    // ---- chunk 0 head: stage, first issue (no fold pending yet) ----
    {
        const uint4* src = (const uint4*)bfr + ((size_t)s * CS) * 2;
        #pragma unroll
        for (int j = 0; j < 8; ++j)
            ldsB[tid + j * 256] = src[tid + j * 256];
    }
    __syncthreads();
    b0 = lb[boff];
    b1 = lb[64 + boff];
    p0 = mfma_v(av0, b0, zc);
    p1 = mfma_v(av0, b1, zc);
    p2 = mfma_v(av1, b0, zc);
    p3 = mfma_v(av1, b1, zc);
    b0 = lb[128 + boff];                      // prefetch it=1
    b1 = lb[192 + boff];

    for (int chunk = 0; chunk < 4; ++chunk) {
        if (chunk > 0) {
            __syncthreads();                  // all waves done reading lb
            const uint4* src = (const uint4*)bfr
                             + ((size_t)s * CS + (size_t)chunk * 1024) * 2;
            #pragma unroll
            for (int j = 0; j < 8; ++j)
                ldsB[tid + j * 256] = src[tid + j * 256];
            __syncthreads();
            b0 = lb[boff];                    // refresh for it=0 of this chunk
            b1 = lb[64 + boff];
        }
        const int itstart = (chunk == 0) ? 1 : 0;   // chunk0 it0 issued in head

        #pragma unroll 1
        for (int it = itstart; it < 16; ++it) {
            // prefetch next iter's b (wraps at it=15; discarded via refresh/drain)
            nb0 = lb[((it + 1) & 15) * 128 + boff];
            nb1 = lb[((it + 1) & 15) * 128 + 64 + boff];
            // fold pending P (issued >= 1 iteration ago)
            HAZARD_BOX();
            #pragma unroll
            for (int i = 0; i < 16; ++i)
                racc0[i] = fminf(fminf(racc0[i], p0[i]), p1[i]);   // v_min3
            #pragma unroll
            for (int i = 0; i < 16; ++i)
                racc1[i] = fminf(fminf(racc1[i], p2[i]), p3[i]);
            // issue new P (fold reads precede these writes in program order)
            p0 = mfma_v(av0, b0, zc);
            p1 = mfma_v(av0, b1, zc);
            p2 = mfma_v(av1, b0, zc);
            p3 = mfma_v(av1, b1, zc);
            b0 = nb0;
            b1 = nb1;
        }
    }

    // ---- drain: fold the final pending set ----
    HAZARD_BOX();
    #pragma unroll
    for (int i = 0; i < 16; ++i)
        racc0[i] = fminf(fminf(racc0[i], p0[i]), p1[i]);
    #pragma unroll
    for (int i = 0; i < 16; ++i)
        racc1[i] = fminf(fminf(racc1[i], p2[i]), p3[i]);

    // ---- epilogue: LDS transpose-reduce (reuse ldsB) ----
    __syncthreads();
    float* lf = (float*)ldsB;                      // 8192 floats = 4 areas x [64][32]
    const int cg = l31 >> 2, cl = l31 & 3;
    #pragma unroll
    for (int i = 0; i < 16; ++i) {
        const int row0 = (i & 3) + 8 * (i >> 2) + 4 * half;   // m74/m101 C/D map
        const int row1 = row0 + 32;
        lf[w * 2048 + row0 * 32 + ((cg ^ (row0 & 7)) << 2) + cl] = racc0[i];
        lf[w * 2048 + row1 * 32 + ((cg ^ (row1 & 7)) << 2) + cl] = racc1[i];
    }
    __syncthreads();
    {
        const int r = tid & 63, wr = tid >> 6;     // thread <-> block row
        const float4* rowp = (const float4*)(lf + wr * 2048 + r * 32);
        float m0 = 3.0e38f, m1 = 3.0e38f;
        #pragma unroll
        for (int g = 0; g < 8; g += 2) {
            const float4 v0 = rowp[g ^ (r & 7)];
            const float4 v1 = rowp[(g + 1) ^ (r & 7)];
            m0 = fminf(fminf(m0, v0.x), fminf(v0.y, v0.z));
            m0 = fminf(m0, v0.w);
            m1 = fminf(fminf(m1, v1.x), fminf(v1.y, v1.z));
            m1 = fminf(m1, v1.w);
        }
        atomicMin(&mins_u[qblk + wr * 64 + r], enc_f32(fminf(m0, m1)));
    }
}

// Finish: mins hold complete d. sqrt, block-reduce, one atomicAdd.
__global__ __launch_bounds__(256) void chamfer_finish(
    const unsigned* __restrict__ mins_u, float* __restrict__ out, int N)
{
    const int tid = threadIdx.x;
    const int qi = blockIdx.x * 256 + tid;

    float v = sqrtf(fmaxf(dec_f32(mins_u[qi]), 0.0f));

    for (int off = 32; off > 0; off >>= 1) v += __shfl_down(v, off, 64);
    __shared__ float wsum[4];
    if ((tid & 63) == 0) wsum[tid >> 6] = v;
    __syncthreads();
    if (tid == 0) {
        const float bsum = wsum[0] + wsum[1] + wsum[2] + wsum[3];
        atomicAdd(out, bsum * 5.0f / (float)N);  // (mean1+mean2)*0.5*10
    }
}

extern "C" void kernel_launch(void* const* d_in, const int* in_sizes, int n_in,
                              void* d_out, int out_size, void* d_ws, size_t ws_size,
                              hipStream_t stream)
{
    const float* state_x = (const float*)d_in[0];
    const float* target  = (const float*)d_in[1];
    float* out = (float*)d_out;

    const int N = in_sizes[0] / 3;               // 16384
    const int twoN = 2 * N;

    int S = S_SLICES;
    while (S > 1 && (N % (S * 1024)) != 0) S >>= 1;

    // Workspace: mins (2N u32) | AfragS | AfragT | BfragS | BfragT (512KB each).
    char* wsb = (char*)d_ws;
    unsigned* mins_u = (unsigned*)wsb;
    uint4* AfragS = (uint4*)(wsb + (size_t)twoN * 4);
    uint4* AfragT = (uint4*)(wsb + (size_t)twoN * 4 + (size_t)N * 32);
    uint4* BfragS = (uint4*)(wsb + (size_t)twoN * 4 + (size_t)N * 64);
    uint4* BfragT = (uint4*)(wsb + (size_t)twoN * 4 + (size_t)N * 96);

    chamfer_prep<<<twoN / 256, 256, 0, stream>>>(
        state_x, target, AfragS, AfragT, BfragS, BfragT, mins_u, out, N);

    const int rowBlocks = twoN / 256;            // 128 blocks of 256 rows
    chamfer_main<<<rowBlocks * S, 256, 0, stream>>>(
        (const bf16x8*)AfragS, (const bf16x8*)AfragT,
        (const bf16x8*)BfragS, (const bf16x8*)BfragT, mins_u, N, S);

    chamfer_finish<<<twoN / 256, 256, 0, stream>>>(mins_u, out, N);
}

// Round 12
// 81.627 us; speedup vs baseline: 1.0114x; 1.0114x over previous
//
#include <hip/hip_runtime.h>
#include <math.h>

// Chamfer loss, two 16384x3 fp32 clouds.
// R16: R15 falsified intra-wave pipelining. Reconciliation of ALL data:
// no pipe >35% busy; R9/R13 Occupancy 27% == 2 waves/SIMD despite VGPR=84.
// Cause: gfx950 unified VGPR+AGPR budget -- the ~130 regs of f32x16
// accumulator state (racc0/racc1/zc + dest tuples) live in AGPRs, total
// ~212 unified -> 2 waves/SIMD, constant across R6..R15 (all kept 2
// row-tiles). Fix: ONE 32-row tile per wave (live ~90 regs), enforced by
// __launch_bounds__(256,4) -> 4 waves/SIMD; grid 1024 = 4 blocks/CU exact.
// ds-traffic/MFMA doubles (LDS ~7.4us vs MFMA 6.9 vs VALU 6.6 chip-wide,
// three separate pipes, 4 waves to interleave). Hazard box 3x s_nop 7
// (fold min3 reads BOTH dests in its first instruction).

typedef __attribute__((ext_vector_type(8)))  short bf16x8;   // 8 bf16 = 4 VGPR
typedef __attribute__((ext_vector_type(16))) float f32x16;   // MFMA C/D

#define S_SLICES 4    // outer col slices; each block stages 4 chunks of 1024

// Monotone float->uint map: a<b  <=>  enc(a)<enc(b).
__device__ __forceinline__ unsigned enc_f32(float f) {
    int b = __float_as_int(f);
    return (b >= 0) ? ((unsigned)b | 0x80000000u) : ~(unsigned)b;
}
__device__ __forceinline__ float dec_f32(unsigned k) {
    int b = (k & 0x80000000u) ? (int)(k & 0x7FFFFFFFu) : ~(int)k;
    return __int_as_float(b);
}

// fp32 -> bf16 (RNE), and back.
__device__ __forceinline__ unsigned short f2bf(float v) {
    unsigned u = __float_as_uint(v);
    u += 0x7FFFu + ((u >> 16) & 1u);
    return (unsigned short)(u >> 16);
}
__device__ __forceinline__ float bf2f(unsigned short b) {
    unsigned u = ((unsigned)b) << 16;
    return __uint_as_float(u);
}
__device__ __forceinline__ unsigned pk2(unsigned short lo, unsigned short hi) {
    return (unsigned)lo | ((unsigned)hi << 16);
}

__device__ __forceinline__ f32x16 mfma_v(bf16x8 a, bf16x8 b, f32x16 c) {
    f32x16 d;
    asm("v_mfma_f32_32x32x16_bf16 %0, %1, %2, %3"
        : "=&v"(d) : "v"(a), "v"(b), "v"(c));
    return d;
}

// Build A-role and B-role K=16 fragments for every point of both clouds.
// d = |q|^2 + |p|^2 - 2(qh+ql).(ph+pl), all cross terms in the 16 K slots.
// B-role fragments scattered into LDS-friendly order:
//   pos(col j, half h) = (j>>6)*128 + ((j>>5)&1)*64 + h*32 + (j&31).
__global__ __launch_bounds__(256) void chamfer_prep(
    const float* __restrict__ state_x, const float* __restrict__ target,
    uint4* __restrict__ AfragS, uint4* __restrict__ AfragT,
    uint4* __restrict__ BfragS, uint4* __restrict__ BfragT,
    unsigned* __restrict__ mins_u, float* __restrict__ out, int N)
{
    const int p = blockIdx.x * 256 + threadIdx.x;     // [0, 2N)
    const float* src = (p < N) ? state_x : target;
    const int i = (p < N) ? p : p - N;

    const float x = src[3*i+0], y = src[3*i+1], z = src[3*i+2];
    const float n2 = fmaf(x, x, fmaf(y, y, z * z));

    const unsigned short hx = f2bf(x), hy = f2bf(y), hz = f2bf(z);
    const unsigned short lx = f2bf(x - bf2f(hx));
    const unsigned short ly = f2bf(y - bf2f(hy));
    const unsigned short lz = f2bf(z - bf2f(hz));
    const unsigned short mhx = f2bf(-2.0f*x), mhy = f2bf(-2.0f*y), mhz = f2bf(-2.0f*z);
    const unsigned short mlx = f2bf(-2.0f*x - bf2f(mhx));
    const unsigned short mly = f2bf(-2.0f*y - bf2f(mhy));
    const unsigned short mlz = f2bf(-2.0f*z - bf2f(mhz));
    const unsigned short hn = f2bf(n2);
    const unsigned short ln = f2bf(n2 - bf2f(hn));
    const unsigned short ONE = 0x3F80;

    // A-role: [mh(3), ml(3), mh(3), ml(3), hn, ln, 1, 1]
    uint4 A0 = make_uint4(pk2(mhx,mhy), pk2(mhz,mlx), pk2(mly,mlz), pk2(mhx,mhy));
    uint4 A1 = make_uint4(pk2(mhz,mlx), pk2(mly,mlz), pk2(hn,ln),   pk2(ONE,ONE));
    // B-role: [h(3), h(3), l(3), l(3), 1, 1, hn, ln]
    uint4 B0 = make_uint4(pk2(hx,hy), pk2(hz,hx), pk2(hy,hz), pk2(lx,ly));
    uint4 B1 = make_uint4(pk2(lz,lx), pk2(ly,lz), pk2(ONE,ONE), pk2(hn,ln));

    uint4* Aarr = (p < N) ? AfragS : AfragT;
    uint4* Barr = (p < N) ? BfragS : BfragT;
    Aarr[2*i+0] = A0;  Aarr[2*i+1] = A1;

    const int bbase = (i >> 6) * 128 + ((i >> 5) & 1) * 64 + (i & 31);
    Barr[bbase +  0] = B0;   // half 0
    Barr[bbase + 32] = B1;   // half 1

    mins_u[p] = 0xFFFFFFFFu;
    if (p == 0) *out = 0.0f;
}

// Main: block = 4 waves x 32 rows = 128 query rows; 4 staged 1024-col
// chunks. Per iter: 2 ds_read_b128, 2 VGPR-form MFMAs (hazard box),
// 16 min3. __launch_bounds__(256,4) caps unified regs at 128 -> 4 waves/SIMD.
__global__ __launch_bounds__(256, 4) void chamfer_main(
    const bf16x8* __restrict__ AfragS, const bf16x8* __restrict__ AfragT,
    const bf16x8* __restrict__ BfragS, const bf16x8* __restrict__ BfragT,
    unsigned* __restrict__ mins_u, int N, int S)
{
    const int tid  = threadIdx.x;
    const int lane = tid & 63;
    const int l31  = lane & 31;
    const int half = lane >> 5;
    const int w    = tid >> 6;

    const int bs = blockIdx.x / S;            // row-block (128 rows)
    const int s  = blockIdx.x % S;            // outer col slice
    const int qblk = bs * 128;                // [0, 2N), never straddles N

    const bf16x8* afr;
    const bf16x8* bfr;
    if (qblk < N) { afr = AfragT + (size_t)qblk * 2;       bfr = BfragS; }
    else          { afr = AfragS + (size_t)(qblk - N) * 2; bfr = BfragT; }

    const int CS = N / S;                     // cols per outer slice (4096)
    const int NCHUNK = CS / 1024;             // 4 staged chunks of 1024 cols

    __shared__ uint4 ldsB[2048];
    const bf16x8* lb = (const bf16x8*)ldsB;

    // A fragment for this wave's single 32-row tile (rows w*32 .. w*32+31).
    const bf16x8 av = afr[(w * 32 + l31) * 2 + half];

    // B read offset: contiguous per wave: pos = it*128 + tile*64 + half*32 + l31.
    const int boff = half * 32 + l31;

    f32x16 racc, zc;
    #pragma unroll
    for (int i = 0; i < 16; ++i) { racc[i] = 3.0e38f; zc[i] = 0.0f; }

    for (int chunk = 0; chunk < NCHUNK; ++chunk) {
        // ---- stage chunk into LDS (2048 uint4 = 32 KB), coalesced ----
        {
            const uint4* src = (const uint4*)bfr
                             + ((size_t)s * CS + (size_t)chunk * 1024) * 2;
            #pragma unroll
            for (int j = 0; j < 8; ++j)
                ldsB[tid + j * 256] = src[tid + j * 256];
        }
        __syncthreads();

        #pragma unroll 1
        for (int it = 0; it < 16; ++it) {
            const bf16x8 b0 = lb[it * 128 + boff];        // cols it*64    + l31
            const bf16x8 b1 = lb[it * 128 + 64 + boff];   // cols it*64+32 + l31
            f32x16 a0 = mfma_v(av, b0, zc);
            f32x16 a1 = mfma_v(av, b1, zc);
            __builtin_amdgcn_sched_barrier(0);
            asm volatile("s_nop 7");                      // MFMA dest -> VALU gap
            asm volatile("s_nop 7");                      // (first min3 reads BOTH
            asm volatile("s_nop 7");                      //  a0 and a1)
            __builtin_amdgcn_sched_barrier(0);
            #pragma unroll
            for (int i = 0; i < 16; ++i)
                racc[i] = fminf(fminf(racc[i], a0[i]), a1[i]);   // v_min3
        }
        __syncthreads();   // all waves done reading before re-staging
    }

    // ---- epilogue: LDS transpose-reduce (reuse ldsB) ----
    float* lf = (float*)ldsB;                      // 4 areas x [32][32] floats
    const int cg = l31 >> 2, cl = l31 & 3;
    #pragma unroll
    for (int i = 0; i < 16; ++i) {
        const int row = (i & 3) + 8 * (i >> 2) + 4 * half;   // m74/m101 C/D map
        lf[w * 1024 + row * 32 + ((cg ^ (row & 7)) << 2) + cl] = racc[i];
    }
    __syncthreads();
    if (tid < 128) {
        const int r = tid & 31, wr = tid >> 5;     // row within area, area id
        const float4* rowp = (const float4*)(lf + wr * 1024 + r * 32);
        float m0 = 3.0e38f, m1 = 3.0e38f;
        #pragma unroll
        for (int g = 0; g < 8; g += 2) {
            const float4 v0 = rowp[g ^ (r & 7)];
            const float4 v1 = rowp[(g + 1) ^ (r & 7)];
            m0 = fminf(fminf(m0, v0.x), fminf(v0.y, v0.z));
            m0 = fminf(m0, v0.w);
            m1 = fminf(fminf(m1, v1.x), fminf(v1.y, v1.z));
            m1 = fminf(m1, v1.w);
        }
        atomicMin(&mins_u[qblk + wr * 32 + r], enc_f32(fminf(m0, m1)));
    }
}

// Finish: mins hold complete d. sqrt, block-reduce, one atomicAdd.
__global__ __launch_bounds__(256) void chamfer_finish(
    const unsigned* __restrict__ mins_u, float* __restrict__ out, int N)
{
    const int tid = threadIdx.x;
    const int qi = blockIdx.x * 256 + tid;

    float v = sqrtf(fmaxf(dec_f32(mins_u[qi]), 0.0f));

    for (int off = 32; off > 0; off >>= 1) v += __shfl_down(v, off, 64);
    __shared__ float wsum[4];
    if ((tid & 63) == 0) wsum[tid >> 6] = v;
    __syncthreads();
    if (tid == 0) {
        const float bsum = wsum[0] + wsum[1] + wsum[2] + wsum[3];
        atomicAdd(out, bsum * 5.0f / (float)N);  // (mean1+mean2)*0.5*10
    }
}

extern "C" void kernel_launch(void* const* d_in, const int* in_sizes, int n_in,
                              void* d_out, int out_size, void* d_ws, size_t ws_size,
                              hipStream_t stream)
{
    const float* state_x = (const float*)d_in[0];
    const float* target  = (const float*)d_in[1];
    float* out = (float*)d_out;

    const int N = in_sizes[0] / 3;               // 16384
    const int twoN = 2 * N;

    int S = S_SLICES;
    while (S > 1 && (N % (S * 1024)) != 0) S >>= 1;

    // Workspace: mins (2N u32) | AfragS | AfragT | BfragS | BfragT (512KB each).
    char* wsb = (char*)d_ws;
    unsigned* mins_u = (unsigned*)wsb;
    uint4* AfragS = (uint4*)(wsb + (size_t)twoN * 4);
    uint4* AfragT = (uint4*)(wsb + (size_t)twoN * 4 + (size_t)N * 32);
    uint4* BfragS = (uint4*)(wsb + (size_t)twoN * 4 + (size_t)N * 64);
    uint4* BfragT = (uint4*)(wsb + (size_t)twoN * 4 + (size_t)N * 96);

    chamfer_prep<<<twoN / 256, 256, 0, stream>>>(
        state_x, target, AfragS, AfragT, BfragS, BfragT, mins_u, out, N);

    const int rowBlocks = twoN / 128;            // 256 blocks of 128 rows
    chamfer_main<<<rowBlocks * S, 256, 0, stream>>>(
        (const bf16x8*)AfragS, (const bf16x8*)AfragT,
        (const bf16x8*)BfragS, (const bf16x8*)BfragT, mins_u, N, S);

    chamfer_finish<<<twoN / 256, 256, 0, stream>>>(mins_u, out, N);
}

// Round 13
// 81.164 us; speedup vs baseline: 1.0172x; 1.0057x over previous
//
#include <hip/hip_runtime.h>
#include <math.h>

// Chamfer loss, two 16384x3 fp32 clouds.
// R17: ALGORITHMIC 2x. R6..R16 computed the 16384^2 distance matrix TWICE
// (once per direction). But dist1 = row-min(D), dist2 = col-min(D) of the
// SAME matrix D[i,j] = |t_i|^2+|s_j|^2-2 t_i.s_j. One pass, both reductions:
// MFMAs 524K->262K (floor 6.9->3.5us), staging/iters halved. R13 proved
// time is work-proportional -> whatever the residual dilation is, it halves.
// Col path per tile: 8 min3 reg-fold/lane + shfl_xor(32) half-combine
// (m74 map: col=lane&31) + half-wave LDS atomicMin into colmin[1024];
// per-chunk flush -> global atomicMin into mins_u[N..2N). Row path and
// epilogue unchanged. Hazard box verbatim (R11/R12 proved load-bearing).

typedef __attribute__((ext_vector_type(8)))  short bf16x8;   // 8 bf16 = 4 VGPR
typedef __attribute__((ext_vector_type(16))) float f32x16;   // MFMA C/D

#define S_SLICES 8    // col slices; CS = N/S = 2048 cols, 2 chunks of 1024

// Monotone float->uint map: a<b  <=>  enc(a)<enc(b).
__device__ __forceinline__ unsigned enc_f32(float f) {
    int b = __float_as_int(f);
    return (b >= 0) ? ((unsigned)b | 0x80000000u) : ~(unsigned)b;
}
__device__ __forceinline__ float dec_f32(unsigned k) {
    int b = (k & 0x80000000u) ? (int)(k & 0x7FFFFFFFu) : ~(int)k;
    return __int_as_float(b);
}

// fp32 -> bf16 (RNE), and back.
__device__ __forceinline__ unsigned short f2bf(float v) {
    unsigned u = __float_as_uint(v);
    u += 0x7FFFu + ((u >> 16) & 1u);
    return (unsigned short)(u >> 16);
}
__device__ __forceinline__ float bf2f(unsigned short b) {
    unsigned u = ((unsigned)b) << 16;
    return __uint_as_float(u);
}
__device__ __forceinline__ unsigned pk2(unsigned short lo, unsigned short hi) {
    return (unsigned)lo | ((unsigned)hi << 16);
}

__device__ __forceinline__ f32x16 mfma_v(bf16x8 a, bf16x8 b, f32x16 c) {
    f32x16 d;
    asm("v_mfma_f32_32x32x16_bf16 %0, %1, %2, %3"
        : "=&v"(d) : "v"(a), "v"(b), "v"(c));
    return d;
}

// A-role frags for TARGET points (matrix rows), B-role frags for STATE
// points (matrix cols). d = |t|^2+|s|^2-2(th+tl).(sh+sl) in 16 K slots.
// B-role scattered LDS-friendly: pos(col j, half h) =
//   (j>>6)*128 + ((j>>5)&1)*64 + h*32 + (j&31).
__global__ __launch_bounds__(256) void chamfer_prep(
    const float* __restrict__ state_x, const float* __restrict__ target,
    uint4* __restrict__ AfragT, uint4* __restrict__ BfragS,
    unsigned* __restrict__ mins_u, float* __restrict__ out, int N)
{
    const int i = blockIdx.x * 256 + threadIdx.x;     // [0, N)

    // ---- target point i -> A-role fragment ----
    {
        const float x = target[3*i+0], y = target[3*i+1], z = target[3*i+2];
        const float n2 = fmaf(x, x, fmaf(y, y, z * z));
        const unsigned short mhx = f2bf(-2.0f*x), mhy = f2bf(-2.0f*y), mhz = f2bf(-2.0f*z);
        const unsigned short mlx = f2bf(-2.0f*x - bf2f(mhx));
        const unsigned short mly = f2bf(-2.0f*y - bf2f(mhy));
        const unsigned short mlz = f2bf(-2.0f*z - bf2f(mhz));
        const unsigned short hn = f2bf(n2);
        const unsigned short ln = f2bf(n2 - bf2f(hn));
        const unsigned short ONE = 0x3F80;
        // A-role: [mh(3), ml(3), mh(3), ml(3), hn, ln, 1, 1]
        AfragT[2*i+0] = make_uint4(pk2(mhx,mhy), pk2(mhz,mlx), pk2(mly,mlz), pk2(mhx,mhy));
        AfragT[2*i+1] = make_uint4(pk2(mhz,mlx), pk2(mly,mlz), pk2(hn,ln),   pk2(ONE,ONE));
    }

    // ---- state point i -> B-role fragment (scattered) ----
    {
        const float x = state_x[3*i+0], y = state_x[3*i+1], z = state_x[3*i+2];
        const float n2 = fmaf(x, x, fmaf(y, y, z * z));
        const unsigned short hx = f2bf(x), hy = f2bf(y), hz = f2bf(z);
        const unsigned short lx = f2bf(x - bf2f(hx));
        const unsigned short ly = f2bf(y - bf2f(hy));
        const unsigned short lz = f2bf(z - bf2f(hz));
        const unsigned short hn = f2bf(n2);
        const unsigned short ln = f2bf(n2 - bf2f(hn));
        const unsigned short ONE = 0x3F80;
        // B-role: [h(3), h(3), l(3), l(3), 1, 1, hn, ln]
        uint4 B0 = make_uint4(pk2(hx,hy), pk2(hz,hx), pk2(hy,hz), pk2(lx,ly));
        uint4 B1 = make_uint4(pk2(lz,lx), pk2(ly,lz), pk2(ONE,ONE), pk2(hn,ln));
        const int bbase = (i >> 6) * 128 + ((i >> 5) & 1) * 64 + (i & 31);
        BfragS[bbase +  0] = B0;   // half 0
        BfragS[bbase + 32] = B1;   // half 1
    }

    mins_u[i]     = 0xFFFFFFFFu;   // dist1 (target rows)
    mins_u[N + i] = 0xFFFFFFFFu;   // dist2 (state cols)
    if (i == 0) *out = 0.0f;
}

// Main: ONE pass over D. Block = 4 waves x 32 target rows = 128 rows;
// S=8 col slices of 2048, staged in 2 chunks of 1024 cols (32KB LDS).
// Per iter: 2 ds_read_b128, 2 MFMAs (hazard box), 16 row-min3,
// 2x8 col-min3 chains + shfl_xor(32) + half-wave LDS atomicMin.
__global__ __launch_bounds__(256, 4) void chamfer_main(
    const bf16x8* __restrict__ AfragT, const bf16x8* __restrict__ BfragS,
    unsigned* __restrict__ mins_u, int N, int S)
{
    const int tid  = threadIdx.x;
    const int lane = tid & 63;
    const int l31  = lane & 31;
    const int half = lane >> 5;
    const int w    = tid >> 6;

    const int bs = blockIdx.x / S;            // target row-block (128 rows)
    const int s  = blockIdx.x % S;            // col slice
    const int qblk = bs * 128;                // target rows [0, N)

    const bf16x8* afr = AfragT + (size_t)qblk * 2;
    const bf16x8* bfr = BfragS;

    const int CS = N / S;                     // cols per slice (2048)
    const int NCHUNK = CS / 1024;             // 2 chunks of 1024 cols

    __shared__ uint4 ldsB[2048];              // 32 KB staging
    __shared__ unsigned colmin[1024];         // 4 KB per-chunk col mins (enc'd)
    const bf16x8* lb = (const bf16x8*)ldsB;

    // A fragment for this wave's 32-row tile (target rows w*32 .. w*32+31).
    const bf16x8 av = afr[(w * 32 + l31) * 2 + half];

    const int boff = half * 32 + l31;

    f32x16 racc, zc;
    #pragma unroll
    for (int i = 0; i < 16; ++i) { racc[i] = 3.0e38f; zc[i] = 0.0f; }

    for (int chunk = 0; chunk < NCHUNK; ++chunk) {
        // ---- stage chunk (coalesced) + init colmin ----
        {
            const uint4* src = (const uint4*)bfr
                             + ((size_t)s * CS + (size_t)chunk * 1024) * 2;
            #pragma unroll
            for (int j = 0; j < 8; ++j)
                ldsB[tid + j * 256] = src[tid + j * 256];
        }
        #pragma unroll
        for (int j = 0; j < 4; ++j)
            colmin[j * 256 + tid] = 0xFFFFFFFFu;
        __syncthreads();

        #pragma unroll 1
        for (int it = 0; it < 16; ++it) {
            const bf16x8 b0 = lb[it * 128 + boff];        // cols it*64    + l31
            const bf16x8 b1 = lb[it * 128 + 64 + boff];   // cols it*64+32 + l31
            f32x16 a0 = mfma_v(av, b0, zc);
            f32x16 a1 = mfma_v(av, b1, zc);
            __builtin_amdgcn_sched_barrier(0);
            asm volatile("s_nop 7");                      // MFMA dest -> VALU gap
            asm volatile("s_nop 7");
            asm volatile("s_nop 7");
            __builtin_amdgcn_sched_barrier(0);
            // row path: elementwise min across tiles (persistent racc)
            #pragma unroll
            for (int i = 0; i < 16; ++i)
                racc[i] = fminf(fminf(racc[i], a0[i]), a1[i]);   // v_min3
            // col path: per-lane fold over 16 regs (rows), combine halves,
            // half-wave LDS atomicMin into this chunk's colmin.
            float c0 = fminf(a0[0], a0[1]);
            float c1 = fminf(a1[0], a1[1]);
            #pragma unroll
            for (int i = 2; i < 16; i += 2) {
                c0 = fminf(fminf(c0, a0[i]), a0[i + 1]);         // v_min3
                c1 = fminf(fminf(c1, a1[i]), a1[i + 1]);
            }
            c0 = fminf(c0, __shfl_xor(c0, 32, 64));
            c1 = fminf(c1, __shfl_xor(c1, 32, 64));
            if (lane < 32) {
                atomicMin(&colmin[it * 64 + lane],      enc_f32(c0));
                atomicMin(&colmin[it * 64 + 32 + lane], enc_f32(c1));
            }
        }
        __syncthreads();
        // ---- flush chunk col-mins to global (cols are distinct per chunk) ----
        {
            const int colbase = N + s * CS + chunk * 1024;
            #pragma unroll
            for (int j = 0; j < 4; ++j)
                atomicMin(&mins_u[colbase + j * 256 + tid], colmin[j * 256 + tid]);
        }
        __syncthreads();   // flush done before next chunk re-inits colmin
    }

    // ---- epilogue: row-min LDS transpose-reduce (reuse ldsB) ----
    float* lf = (float*)ldsB;                      // 4 areas x [32][32] floats
    const int cg = l31 >> 2, cl = l31 & 3;
    #pragma unroll
    for (int i = 0; i < 16; ++i) {
        const int row = (i & 3) + 8 * (i >> 2) + 4 * half;   // m74/m101 C/D map
        lf[w * 1024 + row * 32 + ((cg ^ (row & 7)) << 2) + cl] = racc[i];
    }
    __syncthreads();
    if (tid < 128) {
        const int r = tid & 31, wr = tid >> 5;     // row within area, area id
        const float4* rowp = (const float4*)(lf + wr * 1024 + r * 32);
        float m0 = 3.0e38f, m1 = 3.0e38f;
        #pragma unroll
        for (int g = 0; g < 8; g += 2) {
            const float4 v0 = rowp[g ^ (r & 7)];
            const float4 v1 = rowp[(g + 1) ^ (r & 7)];
            m0 = fminf(fminf(m0, v0.x), fminf(v0.y, v0.z));
            m0 = fminf(m0, v0.w);
            m1 = fminf(fminf(m1, v1.x), fminf(v1.y, v1.z));
            m1 = fminf(m1, v1.w);
        }
        atomicMin(&mins_u[qblk + wr * 32 + r], enc_f32(fminf(m0, m1)));
    }
}

// Finish: mins_u[0,N)=dist1 rows, [N,2N)=dist2 cols (both complete d).
__global__ __launch_bounds__(256) void chamfer_finish(
    const unsigned* __restrict__ mins_u, float* __restrict__ out, int N)
{
    const int tid = threadIdx.x;
    const int qi = blockIdx.x * 256 + tid;

    float v = sqrtf(fmaxf(dec_f32(mins_u[qi]), 0.0f));

    for (int off = 32; off > 0; off >>= 1) v += __shfl_down(v, off, 64);
    __shared__ float wsum[4];
    if ((tid & 63) == 0) wsum[tid >> 6] = v;
    __syncthreads();
    if (tid == 0) {
        const float bsum = wsum[0] + wsum[1] + wsum[2] + wsum[3];
        atomicAdd(out, bsum * 5.0f / (float)N);  // (mean1+mean2)*0.5*10
    }
}

extern "C" void kernel_launch(void* const* d_in, const int* in_sizes, int n_in,
                              void* d_out, int out_size, void* d_ws, size_t ws_size,
                              hipStream_t stream)
{
    const float* state_x = (const float*)d_in[0];
    const float* target  = (const float*)d_in[1];
    float* out = (float*)d_out;

    const int N = in_sizes[0] / 3;               // 16384
    const int twoN = 2 * N;

    int S = S_SLICES;
    while (S > 1 && (N % (S * 1024)) != 0) S >>= 1;

    // Workspace: mins (2N u32, 128KB) | AfragT (512KB) | BfragS (512KB).
    char* wsb = (char*)d_ws;
    unsigned* mins_u = (unsigned*)wsb;
    uint4* AfragT = (uint4*)(wsb + (size_t)twoN * 4);
    uint4* BfragS = (uint4*)(wsb + (size_t)twoN * 4 + (size_t)N * 32);

    chamfer_prep<<<N / 256, 256, 0, stream>>>(
        state_x, target, AfragT, BfragS, mins_u, out, N);

    const int rowBlocks = N / 128;               // 128 target row-blocks
    chamfer_main<<<rowBlocks * S, 256, 0, stream>>>(
        (const bf16x8*)AfragT, (const bf16x8*)BfragS, mins_u, N, S);

    chamfer_finish<<<twoN / 256, 256, 0, stream>>>(mins_u, out, N);
}